// Round 13
// baseline (58.642 us; speedup 1.0000x reference)
//
#include <hip/hip_runtime.h>
#include <math.h>

#define BDIM 4096
#define DDIM 128
#define EPSF 1e-12f
#define TI 128
#define TJ 64
#define NSPLIT 16
#define NSLICE 256                          // (split,ch) x 8 col-groups
#define ITILES (BDIM / TI)                  // 32
#define JT 12                               // Y-tiles per split (16*12 = 192)
#define FLT_BIG 3.402823466e+38f

typedef __attribute__((ext_vector_type(8))) _Float16 f16x8;
typedef __attribute__((ext_vector_type(16))) float f32x16;
union VU { uint4 u; f16x8 v; };

// global (per-lane addr) -> linear LDS (wave-uniform base + lane*16), 16B/lane
__device__ __forceinline__ void gload_lds16(const void* g, void* l) {
    __builtin_amdgcn_global_load_lds(
        (const __attribute__((address_space(1))) unsigned int*)(uintptr_t)g,
        (__attribute__((address_space(3))) unsigned int*)(unsigned int)(uintptr_t)l,
        16, 0, 0);
}

__device__ __forceinline__ unsigned int pack2h(float x, float y) {
    _Float16 hx = (_Float16)x, hy = (_Float16)y;
    unsigned short ux, uy;
    __builtin_memcpy(&ux, &hx, 2);
    __builtin_memcpy(&uy, &hy, 2);
    return (unsigned int)ux | ((unsigned int)uy << 16);
}

// ---------------- Kernel 0: pack to MFMA-fragment layout + norms + y2c ------
// Xp[mat][sl(16)][row(4096)] : 16B chunk = 8 fp16 (k = sl*8..sl*8+7) of row.
// y2c[mat][row] : u32 = fp16 pair (-hi, -lo) with hi+lo ~= y2/2.
__global__ __launch_bounds__(256) void prep_kernel(
    const float* __restrict__ A, const float* __restrict__ P,
    const float* __restrict__ N, uint4* __restrict__ Xp,
    unsigned int* __restrict__ y2c, float* __restrict__ a2,
    float* __restrict__ dpos) {
    int gid = blockIdx.x * 256 + threadIdx.x;   // 0..65535
    int sl = gid & 15;
    int row = gid >> 4;
    const float4 a0 = *(const float4*)&A[row * DDIM + sl * 8];
    const float4 a1 = *(const float4*)&A[row * DDIM + sl * 8 + 4];
    const float4 p0 = *(const float4*)&P[row * DDIM + sl * 8];
    const float4 p1 = *(const float4*)&P[row * DDIM + sl * 8 + 4];
    const float4 n0 = *(const float4*)&N[row * DDIM + sl * 8];
    const float4 n1 = *(const float4*)&N[row * DDIM + sl * 8 + 4];
    uint4 ca = {pack2h(a0.x, a0.y), pack2h(a0.z, a0.w),
                pack2h(a1.x, a1.y), pack2h(a1.z, a1.w)};
    uint4 cp = {pack2h(p0.x, p0.y), pack2h(p0.z, p0.w),
                pack2h(p1.x, p1.y), pack2h(p1.z, p1.w)};
    uint4 cn = {pack2h(n0.x, n0.y), pack2h(n0.z, n0.w),
                pack2h(n1.x, n1.y), pack2h(n1.z, n1.w)};
    Xp[(0 * 16 + sl) * BDIM + row] = ca;
    Xp[(1 * 16 + sl) * BDIM + row] = cp;
    Xp[(2 * 16 + sl) * BDIM + row] = cn;
    float sa = a0.x*a0.x + a0.y*a0.y + a0.z*a0.z + a0.w*a0.w
             + a1.x*a1.x + a1.y*a1.y + a1.z*a1.z + a1.w*a1.w;
    float sp = p0.x*p0.x + p0.y*p0.y + p0.z*p0.z + p0.w*p0.w
             + p1.x*p1.x + p1.y*p1.y + p1.z*p1.z + p1.w*p1.w;
    float sn = n0.x*n0.x + n0.y*n0.y + n0.z*n0.z + n0.w*n0.w
             + n1.x*n1.x + n1.y*n1.y + n1.z*n1.z + n1.w*n1.w;
    float d0 = a0.x-p0.x, d1 = a0.y-p0.y, d2 = a0.z-p0.z, d3 = a0.w-p0.w;
    float d4 = a1.x-p1.x, d5 = a1.y-p1.y, d6 = a1.z-p1.z, d7 = a1.w-p1.w;
    float sd = d0*d0 + d1*d1 + d2*d2 + d3*d3 + d4*d4 + d5*d5 + d6*d6 + d7*d7;
    #pragma unroll
    for (int off = 1; off < 16; off <<= 1) {
        sa += __shfl_xor(sa, off);
        sp += __shfl_xor(sp, off);
        sn += __shfl_xor(sn, off);
        sd += __shfl_xor(sd, off);
    }
    if (sl == 0) {
        a2[row] = sa;
        dpos[row] = sqrtf(fmaxf(sd, EPSF));
        float ya = 0.5f * sa, yp = 0.5f * sp, yn = 0.5f * sn;
        float ha = (float)(_Float16)ya, hp = (float)(_Float16)yp,
              hn = (float)(_Float16)yn;
        y2c[0 * BDIM + row] = pack2h(-ha, -(ya - ha));
        y2c[1 * BDIM + row] = pack2h(-hp, -(yp - hp));
        y2c[2 * BDIM + row] = pack2h(-hn, -(yn - hn));
    }
}

// ---------------- Kernel 1: fp16 MFMA max of (dot - y2/2), ZERO barriers ----
// grid (32 i-tiles, 16 splits), 4 waves; wave = 64 rows x 32 cols, private
// 2x8KB LDS slice, counted vmcnt self-pacing. The -y2/2 term is FOLDED into
// the GEMM via an extra MFMA (A = {1,1,0..} on k-part 0, B = (-hi,-lo) from
// y2c) so the epilogue is a single fmax per element. hardest^2 = a2 - 2*max.
__global__ __launch_bounds__(256, 2) void minsq_kernel(
    const ushort* __restrict__ Xp, const unsigned int* __restrict__ y2c,
    float* __restrict__ partial) {
    __shared__ __align__(16) ushort pool[4][2][4096];   // 64 KB

    const int tid = threadIdx.x;
    const int w = tid >> 6;
    const int lane = tid & 63;
    const int l31 = lane & 31;
    const int lhi = lane >> 5;
    const int rg = w >> 1;
    const int ch = w & 1;
    const int iTile = blockIdx.x;
    const int split = blockIdx.y;
    const int i0 = iTile * TI;
    const int jt0 = split * JT;
    ushort* const wbase = &pool[w][0][0];

    // A-side constant fragment for the y2 fold: rows all 1 on k0,k1 (k-part 0)
    VU au; au.u = (uint4){lhi == 0 ? 0x3C003C00u : 0u, 0u, 0u, 0u};
    const f16x8 ax = au.v;

    // ---- prologue: stage tile 0 + its y2c, preload A fragments ----
    unsigned int yc_cur, yc_nxt;
    {
        int m = jt0 >> 6, tc = jt0 & 63;
        int rowB = tc * TJ + ch * 32 + l31;
        #pragma unroll
        for (int k = 0; k < 8; ++k) {
            int slB = k * 2 + lhi;
            gload_lds16(Xp + (size_t)((m * 16 + slB) * BDIM + rowB) * 8,
                        wbase + k * 512);
        }
        yc_cur = y2c[m * BDIM + rowB];
    }
    f16x8 a0[8], a1[8];
    {
        int rowA = i0 + rg * 64 + l31;
        #pragma unroll
        for (int t = 0; t < 8; ++t) {
            int slA = t * 2 + lhi;
            a0[t] = *(const f16x8*)(Xp + (size_t)(slA * BDIM + rowA) * 8);
            a1[t] = *(const f16x8*)(Xp + (size_t)(slA * BDIM + rowA + 32) * 8);
        }
    }
    asm volatile("s_waitcnt vmcnt(0)" ::: "memory");
    __builtin_amdgcn_sched_barrier(0);

    float maxv0[16], maxv1[16];
    #pragma unroll
    for (int g = 0; g < 16; ++g) { maxv0[g] = -FLT_BIG; maxv1[g] = -FLT_BIG; }

    #pragma unroll
    for (int idx = 0; idx < JT; ++idx) {
        // issue next tile's staging (8 gload_lds) + its y2c load (1 VMEM)
        if (idx + 1 < JT) {
            int jn = jt0 + idx + 1, mn = jn >> 6, tcn = jn & 63;
            int rowB = tcn * TJ + ch * 32 + l31;
            ushort* dst = wbase + ((idx + 1) & 1) * 4096;
            #pragma unroll
            for (int k = 0; k < 8; ++k) {
                int slB = k * 2 + lhi;
                gload_lds16(Xp + (size_t)((mn * 16 + slB) * BDIM + rowB) * 8,
                            dst + k * 512);
            }
            yc_nxt = y2c[mn * BDIM + rowB];
            __builtin_amdgcn_sched_barrier(0);
            asm volatile("s_waitcnt vmcnt(9)" ::: "memory");  // tile idx ready
        } else {
            asm volatile("s_waitcnt vmcnt(0)" ::: "memory");
        }
        __builtin_amdgcn_sched_barrier(0);

        // B-side y2 fragment: (-hi,-lo) in k0,k1 (k-part-1 lanes are x0)
        VU bu; bu.u = (uint4){yc_cur, 0u, 0u, 0u};
        const f16x8 bx = bu.v;

        const ushort* buf = wbase + (idx & 1) * 4096;
        f32x16 acc0 = {}, acc1 = {};
        __builtin_amdgcn_s_setprio(1);
        acc0 = __builtin_amdgcn_mfma_f32_32x32x16_f16(ax, bx, acc0, 0, 0, 0);
        acc1 = __builtin_amdgcn_mfma_f32_32x32x16_f16(ax, bx, acc1, 0, 0, 0);
        #pragma unroll
        for (int t = 0; t < 8; ++t) {
            f16x8 b = *(const f16x8*)&buf[t * 512 + lane * 8];
            acc0 = __builtin_amdgcn_mfma_f32_32x32x16_f16(a0[t], b, acc0, 0, 0, 0);
            acc1 = __builtin_amdgcn_mfma_f32_32x32x16_f16(a1[t], b, acc1, 0, 0, 0);
        }
        __builtin_amdgcn_s_setprio(0);
        yc_cur = yc_nxt;

        // epilogue: single fmax per element (diag exclusion on 2/192 tiles)
        {
            int jt = jt0 + idx, m = jt >> 6, tc = jt & 63;
            if (m < 2 && (tc >> 1) == iTile) {
                int jg = tc * TJ + ch * 32 + l31;
                #pragma unroll
                for (int g = 0; g < 16; ++g) {
                    int rloc = (g & 3) + 8 * (g >> 2) + 4 * lhi;
                    int ig0 = i0 + rg * 64 + rloc;
                    float c0 = acc0[g];
                    if (ig0 == jg) c0 = -FLT_BIG;
                    maxv0[g] = fmaxf(maxv0[g], c0);
                    float c1 = acc1[g];
                    if (ig0 + 32 == jg) c1 = -FLT_BIG;
                    maxv1[g] = fmaxf(maxv1[g], c1);
                }
            } else {
                #pragma unroll
                for (int g = 0; g < 16; ++g) {
                    maxv0[g] = fmaxf(maxv0[g], acc0[g]);
                    maxv1[g] = fmaxf(maxv1[g], acc1[g]);
                }
            }
        }
    }

    // 2-round column reduce (4:1), then store 8 slices per 32-col group
    #pragma unroll
    for (int off = 1; off < 4; off <<= 1) {
        #pragma unroll
        for (int g = 0; g < 16; ++g) {
            maxv0[g] = fmaxf(maxv0[g], __shfl_xor(maxv0[g], off));
            maxv1[g] = fmaxf(maxv1[g], __shfl_xor(maxv1[g], off));
        }
    }
    if ((l31 & 3) == 0) {
        int slice = (split * 2 + ch) * 8 + (l31 >> 2);
        #pragma unroll
        for (int g = 0; g < 16; ++g) {
            int rloc = (g & 3) + 8 * (g >> 2) + 4 * lhi;
            int ig = i0 + rg * 64 + rloc;
            partial[(size_t)ig * NSLICE + slice] = maxv0[g];
            partial[(size_t)(ig + 32) * NSLICE + slice] = maxv1[g];
        }
    }
}

// ---------------- Kernel 2a: wave-per-row loss, 64-block partial sums -------
__global__ __launch_bounds__(256) void lossA_kernel(
    const float* __restrict__ partial, const float* __restrict__ a2,
    const float* __restrict__ dpos, float* __restrict__ bsum) {
    __shared__ float red[4];
    int w = threadIdx.x >> 6;
    int lane = threadIdx.x & 63;
    int wave = blockIdx.x * 4 + w;          // 0..255
    float sum = 0.f;
    #pragma unroll
    for (int j = 0; j < 16; ++j) {
        int row = wave + 256 * j;
        float4 v = *(const float4*)&partial[(size_t)row * NSLICE + lane * 4];
        float m = fmaxf(fmaxf(v.x, v.y), fmaxf(v.z, v.w));
        #pragma unroll
        for (int off = 32; off; off >>= 1) m = fmaxf(m, __shfl_xor(m, off));
        if (lane == 0) {
            float h2 = a2[row] - 2.0f * m;
            float hardest = sqrtf(fmaxf(h2, EPSF));
            float x = dpos[row] - hardest;
            sum += fmaxf(x, 0.f) + log1pf(expf(-fabsf(x)));
        }
    }
    if (lane == 0) red[w] = sum;
    __syncthreads();
    if (threadIdx.x == 0)
        bsum[blockIdx.x] = red[0] + red[1] + red[2] + red[3];
}

// ---------------- Kernel 2b: final scalar ----------------
__global__ void lossB_kernel(const float* __restrict__ bsum,
                             float* __restrict__ out) {
    float v = bsum[threadIdx.x];            // 64 values
    #pragma unroll
    for (int off = 32; off; off >>= 1) v += __shfl_down(v, off);
    if (threadIdx.x == 0) out[0] = v * (1.0f / BDIM);
}

extern "C" void kernel_launch(void* const* d_in, const int* in_sizes, int n_in,
                              void* d_out, int out_size, void* d_ws, size_t ws_size,
                              hipStream_t stream) {
    const float* A = (const float*)d_in[0];
    const float* P = (const float*)d_in[1];
    const float* N = (const float*)d_in[2];

    float* ws = (float*)d_ws;
    float* a2 = ws;                              // 4096
    float* dpos = ws + BDIM;                     // 4096
    unsigned int* y2c = (unsigned int*)(ws + 2 * BDIM);   // 3*4096
    float* bsum = ws + 5 * BDIM;                 // 64
    float* partial = ws + 5 * BDIM + 64;         // BDIM * 256 (4 MB)
    uint4* Xp = (uint4*)(partial + (size_t)BDIM * NSLICE);  // 3 MB

    prep_kernel<<<256, 256, 0, stream>>>(A, P, N, Xp, y2c, a2, dpos);
    dim3 grid2(ITILES, NSPLIT);
    minsq_kernel<<<grid2, 256, 0, stream>>>((const ushort*)Xp, y2c, partial);
    lossA_kernel<<<64, 256, 0, stream>>>(partial, a2, dpos, bsum);
    lossB_kernel<<<1, 64, 0, stream>>>(bsum, (float*)d_out);
}